// Round 5
// baseline (152.373 us; speedup 1.0000x reference)
//
#include <hip/hip_runtime.h>

// WiredRNN one step. CSR-by-dst gather. Partitioned LDS histogram; rank
// assignment merged into the fill pass via LDS cursors (no global atomics,
// no per-edge rank array). statesT staged as bf16 (N,32) for half gather BW.
// inputs: 0:x(B,512) 1:states(B,N) 2:weight(E) 3:bias(N) 4:response(N)
//         5:edge_src(E int32) 6:edge_dst(E int32)
// out: y(B,256) then new_states(B,N), f32, concatenated flat.

#define BATCH 32
#define N_IN 512
#define N_OUT 256
#define RB 2048      // bins per range (8 KB LDS)
#define CC 16        // edge chunks

static __device__ __forceinline__ unsigned short f2bf(float f) {
    unsigned u = __float_as_uint(f);
    unsigned r = (u + 0x7fffu + ((u >> 16) & 1u)) >> 16;   // RNE
    return (unsigned short)r;
}

// ---- pass1: grid-fused {transpose states (B,N)->(N,32) bf16} +
//             {partitioned LDS hist -> pcounts[bin][c]} ----
__global__ void pass1_kernel(const float* __restrict__ s,
                             unsigned short* __restrict__ sTb, int N, int tgrid,
                             const int* __restrict__ edge_dst,
                             int* __restrict__ pcounts,
                             int E, int R, int chunk) {
    __shared__ int shbuf[RB];            // 8 KB; transpose aliases first 4.2 KB
    if ((int)blockIdx.x < tgrid) {
        float* tile = (float*)shbuf;     // [32][33]
        int tx = threadIdx.x & 31;
        int ty = threadIdx.x >> 5;       // 0..7
        int n0 = blockIdx.x * 32;
        for (int i = ty; i < 32; i += 8) {            // i = b
            int n = n0 + tx;
            tile[i * 33 + tx] = (n < N) ? s[(size_t)i * N + n] : 0.f;
        }
        __syncthreads();
        for (int i = ty; i < 32; i += 8) {            // i = n_local
            int n = n0 + i;
            if (n < N) sTb[(size_t)n * 32 + tx] = f2bf(tile[tx * 33 + i]);
        }
        return;
    }
    int k = blockIdx.x - tgrid;
    int r = k % R;
    int c = k / R;
    int base = r * RB;
    for (int i = threadIdx.x; i < RB; i += 256) shbuf[i] = 0;
    __syncthreads();
    int e0 = c * chunk;
    int e1 = min(e0 + chunk, E);
    for (int e = e0 + (int)threadIdx.x * 4; e < e1; e += 256 * 4) {
        if (e + 3 < e1) {
            int4 d4 = *reinterpret_cast<const int4*>(edge_dst + e);
            int dd[4] = {d4.x, d4.y, d4.z, d4.w};
#pragma unroll
            for (int j = 0; j < 4; ++j) {
                unsigned v = (unsigned)(dd[j] - base);
                if (v < RB && dd[j] >= N_IN) atomicAdd(&shbuf[v], 1);
            }
        } else {
            for (int j = 0; j < 4 && e + j < e1; ++j) {
                int d = edge_dst[e + j];
                unsigned v = (unsigned)(d - base);
                if (v < RB && d >= N_IN) atomicAdd(&shbuf[v], 1);
            }
        }
    }
    __syncthreads();
    // every (bin,c) slot written exactly once across the grid -> no memset
    for (int i = threadIdx.x; i < RB; i += 256)
        pcounts[(size_t)(base + i) * CC + c] = shbuf[i];
}

// ---- 3-stage exclusive scan over M ints, in place ----
__global__ void scanA_kernel(int* __restrict__ data, int* __restrict__ bsums,
                             int M) {
    __shared__ int lds[256];
    size_t base = (size_t)blockIdx.x * 2048 + (size_t)threadIdx.x * 8;
    int v[8];
    if (base + 8 <= (size_t)M) {
        int4 a = *reinterpret_cast<const int4*>(data + base);
        int4 b = *reinterpret_cast<const int4*>(data + base + 4);
        v[0]=a.x; v[1]=a.y; v[2]=a.z; v[3]=a.w;
        v[4]=b.x; v[5]=b.y; v[6]=b.z; v[7]=b.w;
    } else {
        for (int j = 0; j < 8; ++j)
            v[j] = (base + j < (size_t)M) ? data[base + j] : 0;
    }
    int s = 0;
#pragma unroll
    for (int j = 0; j < 8; ++j) s += v[j];
    lds[threadIdx.x] = s;
    __syncthreads();
    for (int off = 1; off < 256; off <<= 1) {
        int t = (threadIdx.x >= (unsigned)off) ? lds[threadIdx.x - off] : 0;
        __syncthreads();
        lds[threadIdx.x] += t;
        __syncthreads();
    }
    int run = lds[threadIdx.x] - s;
    if (base + 8 <= (size_t)M) {
        int o[8];
#pragma unroll
        for (int j = 0; j < 8; ++j) { o[j] = run; run += v[j]; }
        *reinterpret_cast<int4*>(data + base)     = make_int4(o[0],o[1],o[2],o[3]);
        *reinterpret_cast<int4*>(data + base + 4) = make_int4(o[4],o[5],o[6],o[7]);
    } else {
        for (int j = 0; j < 8; ++j) {
            if (base + j < (size_t)M) data[base + j] = run;
            run += v[j];
        }
    }
    if (threadIdx.x == 255) bsums[blockIdx.x] = lds[255];
}

__global__ void scanB_kernel(int* __restrict__ bsums, int n) {
    __shared__ int lds[512];
    int v = ((int)threadIdx.x < n) ? bsums[threadIdx.x] : 0;
    lds[threadIdx.x] = v;
    __syncthreads();
    for (int off = 1; off < 512; off <<= 1) {
        int t = (threadIdx.x >= (unsigned)off) ? lds[threadIdx.x - off] : 0;
        __syncthreads();
        lds[threadIdx.x] += t;
        __syncthreads();
    }
    if ((int)threadIdx.x < n) bsums[threadIdx.x] = lds[threadIdx.x] - v;
}

__global__ void scanC_kernel(int* __restrict__ data,
                             const int* __restrict__ bsums, int M) {
    int add = bsums[blockIdx.x];
    if (add == 0) return;
    size_t base = (size_t)blockIdx.x * 2048 + (size_t)threadIdx.x * 8;
    if (base + 8 <= (size_t)M) {
        int4 a = *reinterpret_cast<const int4*>(data + base);
        int4 b = *reinterpret_cast<const int4*>(data + base + 4);
        a.x+=add; a.y+=add; a.z+=add; a.w+=add;
        b.x+=add; b.y+=add; b.z+=add; b.w+=add;
        *reinterpret_cast<int4*>(data + base)     = a;
        *reinterpret_cast<int4*>(data + base + 4) = b;
    } else {
        for (int j = 0; j < 8; ++j)
            if (base + j < (size_t)M) data[base + j] += add;
    }
}

// ---- fill3: partitioned placement with LDS cursors (rank computed here) ----
__global__ void fill3_kernel(const int* __restrict__ edge_src,
                             const int* __restrict__ edge_dst,
                             const float* __restrict__ weight,
                             const int* __restrict__ offsets,
                             int2* __restrict__ edata,
                             int E, int R, int chunk) {
    __shared__ int cur[RB];
    int r = blockIdx.x % R;
    int c = blockIdx.x / R;
    int base = r * RB;
    for (int i = threadIdx.x; i < RB; i += 256)
        cur[i] = offsets[(size_t)(base + i) * CC + c];
    __syncthreads();
    int e0 = c * chunk;
    int e1 = min(e0 + chunk, E);
    for (int e = e0 + (int)threadIdx.x * 4; e < e1; e += 256 * 4) {
        if (e + 3 < e1) {
            int4 d4 = *reinterpret_cast<const int4*>(edge_dst + e);
            int dd[4] = {d4.x, d4.y, d4.z, d4.w};
#pragma unroll
            for (int j = 0; j < 4; ++j) {
                unsigned v = (unsigned)(dd[j] - base);
                if (v < RB && dd[j] >= N_IN) {
                    int pos = atomicAdd(&cur[v], 1);
                    edata[pos] = make_int2(edge_src[e + j],
                                           __float_as_int(weight[e + j]));
                }
            }
        } else {
            for (int j = 0; j < 4 && e + j < e1; ++j) {
                int d = edge_dst[e + j];
                unsigned v = (unsigned)(d - base);
                if (v < RB && d >= N_IN) {
                    int pos = atomicAdd(&cur[v], 1);
                    edata[pos] = make_int2(edge_src[e + j],
                                           __float_as_int(weight[e + j]));
                }
            }
        }
    }
}

// ---- agg3: one wave per node; 4 edges/wave, 2 packed bf16 batches/lane ----
__global__ void agg3_kernel(const unsigned short* __restrict__ sTb,
                            const int2* __restrict__ edata,
                            const int* __restrict__ offsets,
                            const float* __restrict__ x,
                            const float* __restrict__ bias,
                            const float* __restrict__ response,
                            float* __restrict__ nsT, int N) {
    int node = blockIdx.x * (blockDim.x >> 6) + (threadIdx.x >> 6);
    if (node >= N) return;
    int lane = threadIdx.x & 63;
    int q = lane & 15;        // batch pair: b0=2q, b1=2q+1
    int p = lane >> 4;        // edge slot 0..3
    if (node < N_IN) {
        if (p == 0) {
            float2 v;
            v.x = x[(2 * q) * N_IN + node];
            v.y = x[(2 * q + 1) * N_IN + node];
            *reinterpret_cast<float2*>(&nsT[(size_t)node * 32 + 2 * q]) = v;
        }
        return;
    }
    int beg = offsets[(size_t)node * CC];
    int end = offsets[(size_t)(node + 1) * CC];
    float a0 = 0.f, a1 = 0.f;
    for (int e = beg + p; e < end; e += 4) {
        int2 ed = edata[e];
        unsigned u = *reinterpret_cast<const unsigned*>(
            sTb + (size_t)ed.x * 32 + 2 * q);
        float w = __int_as_float(ed.y);
        a0 += w * __uint_as_float(u << 16);
        a1 += w * __uint_as_float(u & 0xffff0000u);
    }
    a0 += __shfl_xor(a0, 16, 64);
    a0 += __shfl_xor(a0, 32, 64);
    a1 += __shfl_xor(a1, 16, 64);
    a1 += __shfl_xor(a1, 32, 64);
    if (p == 0) {
        float bi = bias[node], rs = response[node];
        float2 z;
        z.x = tanhf(bi + rs * a0);
        z.y = tanhf(bi + rs * a1);
        *reinterpret_cast<float2*>(&nsT[(size_t)node * 32 + 2 * q]) = z;
    }
}

// ---- transpose nsT (N,32) -> ns (B,N), extract y ----
__global__ void transpose_out_kernel(const float* __restrict__ nsT,
                                     float* __restrict__ ns,
                                     float* __restrict__ y, int N) {
    __shared__ float tile[32][33];
    int n0 = blockIdx.x * 32;
    int tx = threadIdx.x;   // 0..31
    int ty = threadIdx.y;   // 0..7
    for (int i = ty; i < 32; i += 8) {           // i = n_local
        int n = n0 + i;
        tile[i][tx] = (n < N) ? nsT[(size_t)n * 32 + tx] : 0.f;  // b = tx
    }
    __syncthreads();
    for (int i = ty; i < 32; i += 8) {           // i = b
        int n = n0 + tx;
        if (n < N) {
            float v = tile[tx][i];
            ns[(size_t)i * N + n] = v;
            int k = n - (N - N_OUT);
            if (k >= 0) y[i * N_OUT + k] = v;
        }
    }
}

// ---- last-resort fallback (round-1) kernels ----
__global__ void edge_kernel_fb(const float* __restrict__ states,
                               const float* __restrict__ weight,
                               const int* __restrict__ edge_src,
                               const int* __restrict__ edge_dst,
                               float* __restrict__ agg, int E, int N) {
    int e = blockIdx.x * blockDim.x + threadIdx.x;
    if (e >= E) return;
    int s = edge_src[e];
    int d = edge_dst[e];
    float w = weight[e];
#pragma unroll
    for (int b = 0; b < BATCH; ++b)
        atomicAdd(agg + (size_t)b * N + d, w * states[(size_t)b * N + s]);
}

__global__ void finish_kernel_fb(const float* __restrict__ x,
                                 const float* __restrict__ agg,
                                 const float* __restrict__ bias,
                                 const float* __restrict__ response,
                                 float* __restrict__ y, float* __restrict__ ns,
                                 int N) {
    int n = blockIdx.x * blockDim.x + threadIdx.x;
    int b = blockIdx.y;
    if (n >= N) return;
    float v;
    if (n < N_IN) v = x[b * N_IN + n];
    else          v = tanhf(bias[n] + response[n] * agg[(size_t)b * N + n]);
    ns[(size_t)b * N + n] = v;
    int n0 = N - N_OUT;
    if (n >= n0) y[b * N_OUT + (n - n0)] = v;
}

extern "C" void kernel_launch(void* const* d_in, const int* in_sizes, int n_in,
                              void* d_out, int out_size, void* d_ws, size_t ws_size,
                              hipStream_t stream) {
    const float* x        = (const float*)d_in[0];
    const float* states   = (const float*)d_in[1];
    const float* weight   = (const float*)d_in[2];
    const float* bias     = (const float*)d_in[3];
    const float* response = (const float*)d_in[4];
    const int*   edge_src = (const int*)d_in[5];
    const int*   edge_dst = (const int*)d_in[6];

    int N = in_sizes[3];          // 50000
    int E = in_sizes[5];          // 800000

    float* y  = (float*)d_out;                   // (B, N_OUT)
    float* ns = (float*)d_out + BATCH * N_OUT;   // (B, N)

    const int blk = 256;
    int tgrid = (N + 31) / 32;                   // 1563
    int egrid = (E + blk - 1) / blk;

    int R     = (N + RB - 1) / RB;               // 25
    int NBINS = R * RB;                          // 51200
    int M     = NBINS * CC;                      // 819200
    int chunk = (((E + CC - 1) / CC) + 3) & ~3;  // 50000
    int nblkA = (M + 2047) / 2048;               // 400

    size_t edata_bytes   = ((size_t)E * 8 + 15) & ~(size_t)15;
    size_t sTb_bytes     = ((size_t)N * 32 * 2 + 15) & ~(size_t)15;
    size_t nsT_bytes     = ((size_t)N * 32 * 4 + 15) & ~(size_t)15;
    size_t pcounts_bytes = ((size_t)M * 4 + 15) & ~(size_t)15;
    size_t bsum_bytes    = ((size_t)nblkA * 4 + 15) & ~(size_t)15;
    size_t needed = edata_bytes + sTb_bytes + nsT_bytes + pcounts_bytes +
                    bsum_bytes + 64;

    if (ws_size < needed || nblkA > 512) {
        float* agg = (float*)d_ws;
        hipMemsetAsync(agg, 0, (size_t)BATCH * N * sizeof(float), stream);
        edge_kernel_fb<<<egrid, blk, 0, stream>>>(states, weight, edge_src,
                                                  edge_dst, agg, E, N);
        dim3 fgrid((N + blk - 1) / blk, BATCH);
        finish_kernel_fb<<<fgrid, blk, 0, stream>>>(x, agg, bias, response,
                                                    y, ns, N);
        return;
    }

    char* p = (char*)d_ws;
    int2*           edata   = (int2*)p;           p += edata_bytes;
    unsigned short* sTb     = (unsigned short*)p; p += sTb_bytes;
    float*          nsT     = (float*)p;          p += nsT_bytes;
    int*            pcounts = (int*)p;            p += pcounts_bytes; // -> offsets
    int*            bsums   = (int*)p;            p += bsum_bytes;

    // 1. transpose(bf16) || partitioned hist (no global atomics, no memset)
    pass1_kernel<<<tgrid + R * CC, blk, 0, stream>>>(
        states, sTb, N, tgrid, edge_dst, pcounts, E, R, chunk);

    // 2. exclusive scan of pcounts[bin][c], in place
    scanA_kernel<<<nblkA, 256, 0, stream>>>(pcounts, bsums, M);
    scanB_kernel<<<1, 512, 0, stream>>>(bsums, nblkA);
    scanC_kernel<<<nblkA, 256, 0, stream>>>(pcounts, bsums, M);

    // 3. placement with LDS cursors (rank computed on the fly)
    fill3_kernel<<<R * CC, blk, 0, stream>>>(edge_src, edge_dst, weight,
                                             pcounts, edata, E, R, chunk);

    // 4. gather-aggregate + tanh
    int waves_per_blk = blk / 64;  // 4
    int agrid = (N + waves_per_blk - 1) / waves_per_blk;
    agg3_kernel<<<agrid, blk, 0, stream>>>(sTb, edata, pcounts, x,
                                           bias, response, nsT, N);

    // 5. transpose out + y slice
    transpose_out_kernel<<<tgrid, dim3(32, 8), 0, stream>>>(nsT, ns, y, N);
}

// Round 6
// 93.086 us; speedup vs baseline: 1.6369x; 1.6369x over previous
//
#include <hip/hip_runtime.h>

// WiredRNN one step. CSR-by-dst gather. Partitioned LDS histogram; rank
// assignment merged into fill via LDS cursors. 1024-thread blocks for the
// partitioned passes (fixes grid starvation / 15% occupancy of round 5).
// scanC fused into fill/agg (consumers add bsums[idx>>11] themselves).
// inputs: 0:x(B,512) 1:states(B,N) 2:weight(E) 3:bias(N) 4:response(N)
//         5:edge_src(E int32) 6:edge_dst(E int32)
// out: y(B,256) then new_states(B,N), f32, concatenated flat.

#define BATCH 32
#define N_IN 512
#define N_OUT 256
#define RB 2048      // bins per range (8 KB LDS)
#define CC 16        // edge chunks

static __device__ __forceinline__ unsigned short f2bf(float f) {
    unsigned u = __float_as_uint(f);
    unsigned r = (u + 0x7fffu + ((u >> 16) & 1u)) >> 16;   // RNE
    return (unsigned short)r;
}

// ---- pass1 (1024 thr): grid-fused {transpose states (B,N)->(N,32) bf16} +
//             {partitioned LDS hist -> pcounts[bin][c]} ----
__global__ void pass1_kernel(const float* __restrict__ s,
                             unsigned short* __restrict__ sTb, int N, int tgrid,
                             const int* __restrict__ edge_dst,
                             int* __restrict__ pcounts,
                             int E, int R, int chunk) {
    __shared__ int shbuf[RB];            // 8 KB; transpose aliases first 4.2 KB
    if ((int)blockIdx.x < tgrid) {
        float* tile = (float*)shbuf;     // [32][33]
        int tx = threadIdx.x & 31;
        int ty = threadIdx.x >> 5;       // 0..31
        int n0 = blockIdx.x * 32;
        int n = n0 + tx;
        tile[ty * 33 + tx] = (n < N) ? s[(size_t)ty * N + n] : 0.f;  // ty=b
        __syncthreads();
        int nn = n0 + ty;
        if (nn < N) sTb[(size_t)nn * 32 + tx] = f2bf(tile[tx * 33 + ty]);
        return;
    }
    int k = blockIdx.x - tgrid;
    int r = k % R;
    int c = k / R;
    int base = r * RB;
    for (int i = threadIdx.x; i < RB; i += 1024) shbuf[i] = 0;
    __syncthreads();
    int e0 = c * chunk;
    int e1 = min(e0 + chunk, E);
    for (int e = e0 + (int)threadIdx.x * 4; e < e1; e += 1024 * 4) {
        if (e + 3 < e1) {
            int4 d4 = *reinterpret_cast<const int4*>(edge_dst + e);
            int dd[4] = {d4.x, d4.y, d4.z, d4.w};
#pragma unroll
            for (int j = 0; j < 4; ++j) {
                unsigned v = (unsigned)(dd[j] - base);
                if (v < RB && dd[j] >= N_IN) atomicAdd(&shbuf[v], 1);
            }
        } else {
            for (int j = 0; j < 4 && e + j < e1; ++j) {
                int d = edge_dst[e + j];
                unsigned v = (unsigned)(d - base);
                if (v < RB && d >= N_IN) atomicAdd(&shbuf[v], 1);
            }
        }
    }
    __syncthreads();
    // every (bin,c) slot written exactly once across the grid -> no memset
    for (int i = threadIdx.x; i < RB; i += 1024)
        pcounts[(size_t)(base + i) * CC + c] = shbuf[i];
}

// ---- scanA: per-block (2048 elts) exclusive scan in place + block sums ----
__global__ void scanA_kernel(int* __restrict__ data, int* __restrict__ bsums,
                             int M) {
    __shared__ int lds[256];
    size_t base = (size_t)blockIdx.x * 2048 + (size_t)threadIdx.x * 8;
    int v[8];
    if (base + 8 <= (size_t)M) {
        int4 a = *reinterpret_cast<const int4*>(data + base);
        int4 b = *reinterpret_cast<const int4*>(data + base + 4);
        v[0]=a.x; v[1]=a.y; v[2]=a.z; v[3]=a.w;
        v[4]=b.x; v[5]=b.y; v[6]=b.z; v[7]=b.w;
    } else {
        for (int j = 0; j < 8; ++j)
            v[j] = (base + j < (size_t)M) ? data[base + j] : 0;
    }
    int s = 0;
#pragma unroll
    for (int j = 0; j < 8; ++j) s += v[j];
    lds[threadIdx.x] = s;
    __syncthreads();
    for (int off = 1; off < 256; off <<= 1) {
        int t = (threadIdx.x >= (unsigned)off) ? lds[threadIdx.x - off] : 0;
        __syncthreads();
        lds[threadIdx.x] += t;
        __syncthreads();
    }
    int run = lds[threadIdx.x] - s;
    if (base + 8 <= (size_t)M) {
        int o[8];
#pragma unroll
        for (int j = 0; j < 8; ++j) { o[j] = run; run += v[j]; }
        *reinterpret_cast<int4*>(data + base)     = make_int4(o[0],o[1],o[2],o[3]);
        *reinterpret_cast<int4*>(data + base + 4) = make_int4(o[4],o[5],o[6],o[7]);
    } else {
        for (int j = 0; j < 8; ++j) {
            if (base + j < (size_t)M) data[base + j] = run;
            run += v[j];
        }
    }
    if (threadIdx.x == 255) bsums[blockIdx.x] = lds[255];
}

// ---- scanB: exclusive scan of block sums (single block) ----
__global__ void scanB_kernel(int* __restrict__ bsums, int n) {
    __shared__ int lds[512];
    int v = ((int)threadIdx.x < n) ? bsums[threadIdx.x] : 0;
    lds[threadIdx.x] = v;
    __syncthreads();
    for (int off = 1; off < 512; off <<= 1) {
        int t = (threadIdx.x >= (unsigned)off) ? lds[threadIdx.x - off] : 0;
        __syncthreads();
        lds[threadIdx.x] += t;
        __syncthreads();
    }
    if ((int)threadIdx.x < n) bsums[threadIdx.x] = lds[threadIdx.x] - v;
}

// ---- fill3 (1024 thr): placement with LDS cursors; global offset =
//      pcounts[idx] + bsums[idx>>11] (scanC fused) ----
__global__ void fill3_kernel(const int* __restrict__ edge_src,
                             const int* __restrict__ edge_dst,
                             const float* __restrict__ weight,
                             const int* __restrict__ offsets,
                             const int* __restrict__ bsums,
                             int2* __restrict__ edata,
                             int E, int R, int chunk) {
    __shared__ int cur[RB];
    int r = blockIdx.x % R;
    int c = blockIdx.x / R;
    int base = r * RB;
    for (int i = threadIdx.x; i < RB; i += 1024) {
        size_t idx = (size_t)(base + i) * CC + c;
        cur[i] = offsets[idx] + bsums[idx >> 11];
    }
    __syncthreads();
    int e0 = c * chunk;
    int e1 = min(e0 + chunk, E);
    for (int e = e0 + (int)threadIdx.x * 4; e < e1; e += 1024 * 4) {
        if (e + 3 < e1) {
            int4 d4 = *reinterpret_cast<const int4*>(edge_dst + e);
            int dd[4] = {d4.x, d4.y, d4.z, d4.w};
#pragma unroll
            for (int j = 0; j < 4; ++j) {
                unsigned v = (unsigned)(dd[j] - base);
                if (v < RB && dd[j] >= N_IN) {
                    int pos = atomicAdd(&cur[v], 1);
                    edata[pos] = make_int2(edge_src[e + j],
                                           __float_as_int(weight[e + j]));
                }
            }
        } else {
            for (int j = 0; j < 4 && e + j < e1; ++j) {
                int d = edge_dst[e + j];
                unsigned v = (unsigned)(d - base);
                if (v < RB && d >= N_IN) {
                    int pos = atomicAdd(&cur[v], 1);
                    edata[pos] = make_int2(edge_src[e + j],
                                           __float_as_int(weight[e + j]));
                }
            }
        }
    }
}

// ---- agg3: one wave per node; 4 edges/wave, 2 packed bf16 batches/lane ----
__global__ void agg3_kernel(const unsigned short* __restrict__ sTb,
                            const int2* __restrict__ edata,
                            const int* __restrict__ offsets,
                            const int* __restrict__ bsums,
                            const float* __restrict__ x,
                            const float* __restrict__ bias,
                            const float* __restrict__ response,
                            float* __restrict__ nsT, int N) {
    int node = blockIdx.x * (blockDim.x >> 6) + (threadIdx.x >> 6);
    if (node >= N) return;
    int lane = threadIdx.x & 63;
    int q = lane & 15;        // batch pair: b0=2q, b1=2q+1
    int p = lane >> 4;        // edge slot 0..3
    if (node < N_IN) {
        if (p == 0) {
            float2 v;
            v.x = x[(2 * q) * N_IN + node];
            v.y = x[(2 * q + 1) * N_IN + node];
            *reinterpret_cast<float2*>(&nsT[(size_t)node * 32 + 2 * q]) = v;
        }
        return;
    }
    size_t i0 = (size_t)node * CC;
    size_t i1 = (size_t)(node + 1) * CC;
    int beg = offsets[i0] + bsums[i0 >> 11];
    int end = offsets[i1] + bsums[i1 >> 11];
    float a0 = 0.f, a1 = 0.f;
    for (int e = beg + p; e < end; e += 4) {
        int2 ed = edata[e];
        unsigned u = *reinterpret_cast<const unsigned*>(
            sTb + (size_t)ed.x * 32 + 2 * q);
        float w = __int_as_float(ed.y);
        a0 += w * __uint_as_float(u << 16);
        a1 += w * __uint_as_float(u & 0xffff0000u);
    }
    a0 += __shfl_xor(a0, 16, 64);
    a0 += __shfl_xor(a0, 32, 64);
    a1 += __shfl_xor(a1, 16, 64);
    a1 += __shfl_xor(a1, 32, 64);
    if (p == 0) {
        float bi = bias[node], rs = response[node];
        float2 z;
        z.x = tanhf(bi + rs * a0);
        z.y = tanhf(bi + rs * a1);
        *reinterpret_cast<float2*>(&nsT[(size_t)node * 32 + 2 * q]) = z;
    }
}

// ---- transpose nsT (N,32) -> ns (B,N), extract y ----
__global__ void transpose_out_kernel(const float* __restrict__ nsT,
                                     float* __restrict__ ns,
                                     float* __restrict__ y, int N) {
    __shared__ float tile[32][33];
    int n0 = blockIdx.x * 32;
    int tx = threadIdx.x;   // 0..31
    int ty = threadIdx.y;   // 0..7
    for (int i = ty; i < 32; i += 8) {           // i = n_local
        int n = n0 + i;
        tile[i][tx] = (n < N) ? nsT[(size_t)n * 32 + tx] : 0.f;  // b = tx
    }
    __syncthreads();
    for (int i = ty; i < 32; i += 8) {           // i = b
        int n = n0 + tx;
        if (n < N) {
            float v = tile[tx][i];
            ns[(size_t)i * N + n] = v;
            int k = n - (N - N_OUT);
            if (k >= 0) y[i * N_OUT + k] = v;
        }
    }
}

// ---- last-resort fallback (round-1) kernels ----
__global__ void edge_kernel_fb(const float* __restrict__ states,
                               const float* __restrict__ weight,
                               const int* __restrict__ edge_src,
                               const int* __restrict__ edge_dst,
                               float* __restrict__ agg, int E, int N) {
    int e = blockIdx.x * blockDim.x + threadIdx.x;
    if (e >= E) return;
    int s = edge_src[e];
    int d = edge_dst[e];
    float w = weight[e];
#pragma unroll
    for (int b = 0; b < BATCH; ++b)
        atomicAdd(agg + (size_t)b * N + d, w * states[(size_t)b * N + s]);
}

__global__ void finish_kernel_fb(const float* __restrict__ x,
                                 const float* __restrict__ agg,
                                 const float* __restrict__ bias,
                                 const float* __restrict__ response,
                                 float* __restrict__ y, float* __restrict__ ns,
                                 int N) {
    int n = blockIdx.x * blockDim.x + threadIdx.x;
    int b = blockIdx.y;
    if (n >= N) return;
    float v;
    if (n < N_IN) v = x[b * N_IN + n];
    else          v = tanhf(bias[n] + response[n] * agg[(size_t)b * N + n]);
    ns[(size_t)b * N + n] = v;
    int n0 = N - N_OUT;
    if (n >= n0) y[b * N_OUT + (n - n0)] = v;
}

extern "C" void kernel_launch(void* const* d_in, const int* in_sizes, int n_in,
                              void* d_out, int out_size, void* d_ws, size_t ws_size,
                              hipStream_t stream) {
    const float* x        = (const float*)d_in[0];
    const float* states   = (const float*)d_in[1];
    const float* weight   = (const float*)d_in[2];
    const float* bias     = (const float*)d_in[3];
    const float* response = (const float*)d_in[4];
    const int*   edge_src = (const int*)d_in[5];
    const int*   edge_dst = (const int*)d_in[6];

    int N = in_sizes[3];          // 50000
    int E = in_sizes[5];          // 800000

    float* y  = (float*)d_out;                   // (B, N_OUT)
    float* ns = (float*)d_out + BATCH * N_OUT;   // (B, N)

    int tgrid = (N + 31) / 32;                   // 1563
    int egrid = (E + 255) / 256;

    int R     = (N + RB - 1) / RB;               // 25
    int NBINS = R * RB;                          // 51200
    int M     = NBINS * CC;                      // 819200
    int chunk = (((E + CC - 1) / CC) + 3) & ~3;  // 50000
    int nblkA = (M + 2047) / 2048;               // 400

    size_t edata_bytes   = ((size_t)E * 8 + 15) & ~(size_t)15;
    size_t sTb_bytes     = ((size_t)N * 32 * 2 + 15) & ~(size_t)15;
    size_t nsT_bytes     = ((size_t)N * 32 * 4 + 15) & ~(size_t)15;
    size_t pcounts_bytes = ((size_t)M * 4 + 15) & ~(size_t)15;
    size_t bsum_bytes    = ((size_t)nblkA * 4 + 15) & ~(size_t)15;
    size_t needed = edata_bytes + sTb_bytes + nsT_bytes + pcounts_bytes +
                    bsum_bytes + 64;

    if (ws_size < needed || nblkA > 512) {
        float* agg = (float*)d_ws;
        hipMemsetAsync(agg, 0, (size_t)BATCH * N * sizeof(float), stream);
        edge_kernel_fb<<<egrid, 256, 0, stream>>>(states, weight, edge_src,
                                                  edge_dst, agg, E, N);
        dim3 fgrid((N + 255) / 256, BATCH);
        finish_kernel_fb<<<fgrid, 256, 0, stream>>>(x, agg, bias, response,
                                                    y, ns, N);
        return;
    }

    char* p = (char*)d_ws;
    int2*           edata   = (int2*)p;           p += edata_bytes;
    unsigned short* sTb     = (unsigned short*)p; p += sTb_bytes;
    float*          nsT     = (float*)p;          p += nsT_bytes;
    int*            pcounts = (int*)p;            p += pcounts_bytes; // -> offsets
    int*            bsums   = (int*)p;            p += bsum_bytes;

    // 1. transpose(bf16) || partitioned hist — 1024-thread blocks
    pass1_kernel<<<tgrid + R * CC, 1024, 0, stream>>>(
        states, sTb, N, tgrid, edge_dst, pcounts, E, R, chunk);

    // 2. two-level exclusive scan (scanC fused into consumers)
    scanA_kernel<<<nblkA, 256, 0, stream>>>(pcounts, bsums, M);
    scanB_kernel<<<1, 512, 0, stream>>>(bsums, nblkA);

    // 3. placement with LDS cursors — 1024-thread blocks
    fill3_kernel<<<R * CC, 1024, 0, stream>>>(edge_src, edge_dst, weight,
                                              pcounts, bsums, edata, E, R, chunk);

    // 4. gather-aggregate + tanh
    int agrid = (N + 3) / 4;   // 4 waves (nodes) per 256-thread block
    agg3_kernel<<<agrid, 256, 0, stream>>>(sTb, edata, pcounts, bsums, x,
                                           bias, response, nsT, N);

    // 5. transpose out + y slice
    transpose_out_kernel<<<tgrid, dim3(32, 8), 0, stream>>>(nsT, ns, y, N);
}